// Round 1
// baseline (17158.363 us; speedup 1.0000x reference)
//
#include <hip/hip_runtime.h>
#include <hip/hip_fp16.h>

#define NP 16384
#define MC 4096
#define R2F 0.04f
#define MAXC 256

typedef _Float16 f16x8 __attribute__((ext_vector_type(8)));
typedef float f32x4 __attribute__((ext_vector_type(4)));

// Reference-matching squared distance: (dx*dx + dy*dy) + dz*dz, no fma contraction.
__device__ __forceinline__ float sqdist3(float ax, float ay, float az,
                                         float bx, float by, float bz) {
    float dx = ax - bx, dy = ay - by, dz = az - bz;
    return __fadd_rn(__fadd_rn(__fmul_rn(dx, dx), __fmul_rn(dy, dy)), __fmul_rn(dz, dz));
}

// ---------------- prep: pos4 + transposed f16 weights ----------------
__global__ __launch_bounds__(256) void k_prep(const float* __restrict__ x,
    const float* __restrict__ W1, const float* __restrict__ W2, const float* __restrict__ W3,
    float4* __restrict__ pos4, _Float16* __restrict__ w1t,
    _Float16* __restrict__ w2t, _Float16* __restrict__ w3t)
{
    int tid = blockIdx.x * 256 + threadIdx.x;
    if (tid < NP) {
        long b = (long)tid * 131;
        float4 p; p.x = x[b]; p.y = x[b + 1]; p.z = x[b + 2]; p.w = 0.f;
        pos4[tid] = p;
    } else if (tid < NP + 128 * 168) {
        int i = tid - NP; int c = i / 168, k = i % 168;
        w1t[i] = (k < 131) ? (_Float16)W1[k * 128 + c] : (_Float16)0.f;
    } else if (tid < NP + 128 * 168 + 128 * 136) {
        int i = tid - (NP + 128 * 168); int c = i / 136, k = i % 136;
        w2t[i] = (k < 128) ? (_Float16)W2[k * 128 + c] : (_Float16)0.f;
    } else if (tid < NP + 128 * 168 + 128 * 136 + 256 * 136) {
        int i = tid - (NP + 128 * 168 + 128 * 136); int c = i / 136, k = i % 136;
        w3t[i] = (k < 128) ? (_Float16)W3[k * 256 + c] : (_Float16)0.f;
    }
}

// ---------------- FPS: single workgroup, state in registers ----------------
__global__ __launch_bounds__(1024) void k_fps(const float4* __restrict__ pos4,
                                              float4* __restrict__ centers)
{
    __shared__ float s_c[3];
    __shared__ float s_redv[16];
    __shared__ int s_redi[16];
    const int t = threadIdx.x;
    const int lane = t & 63;
    const int wv = t >> 6;
    float px[16], py[16], pz[16], md[16];
    #pragma unroll
    for (int i = 0; i < 16; i++) {
        float4 p = pos4[t * 16 + i];
        px[i] = p.x; py[i] = p.y; pz[i] = p.z;
        md[i] = __builtin_inff();
    }
    if (t == 0) { s_c[0] = px[0]; s_c[1] = py[0]; s_c[2] = pz[0]; }
    __syncthreads();
    for (int m = 0; m < MC; m++) {
        float cx = s_c[0], cy = s_c[1], cz = s_c[2];
        if (t == 0) centers[m] = make_float4(cx, cy, cz, 0.f);
        float lv = -1.f;
        #pragma unroll
        for (int i = 0; i < 16; i++) {
            float d = sqdist3(px[i], py[i], pz[i], cx, cy, cz);
            md[i] = fminf(md[i], d);
            lv = fmaxf(lv, md[i]);
        }
        #pragma unroll
        for (int off = 1; off < 64; off <<= 1)
            lv = fmaxf(lv, __shfl_xor(lv, off));
        if (lane == 0) s_redv[wv] = lv;
        __syncthreads();
        float gmax = s_redv[0];
        #pragma unroll
        for (int j = 1; j < 16; j++) gmax = fmaxf(gmax, s_redv[j]);
        // first (lowest-index) point equal to gmax; thread ranges are index-contiguous
        int h = -1;
        #pragma unroll
        for (int i = 15; i >= 0; i--) if (md[i] == gmax) h = i;
        unsigned long long bal = __ballot(h >= 0);
        if (bal != 0ull) {
            int f = __builtin_ctzll(bal);
            if (lane == f) s_redi[wv] = (t << 4) | h;
        } else if (lane == 0) {
            s_redi[wv] = 0x7fffffff;
        }
        __syncthreads();
        int win = s_redi[0];
        #pragma unroll
        for (int j = 1; j < 16; j++) win = min(win, s_redi[j]);
        if (t == (win >> 4)) {
            int i = win & 15;
            s_c[0] = px[i]; s_c[1] = py[i]; s_c[2] = pz[i];
        }
        __syncthreads();
    }
}

// ---------------- kNN within radius: one wave per center ----------------
__global__ __launch_bounds__(256) void k_knn(const float4* __restrict__ pos4,
                                             const float4* __restrict__ centers,
                                             int* __restrict__ nbr_cnt,
                                             int* __restrict__ nbr_idx)
{
    __shared__ int s_ci[4][MAXC];
    __shared__ float s_cd[4][MAXC];
    const int t = threadIdx.x, lane = t & 63, wv = t >> 6;
    const int m = blockIdx.x * 4 + wv;
    float4 c = centers[m];
    int base = 0;
    for (int ch = 0; ch < NP / 64; ch++) {
        int p = ch * 64 + lane;
        float4 q = pos4[p];
        float d2 = sqdist3(q.x, q.y, q.z, c.x, c.y, c.z);
        bool pred = (d2 <= R2F);
        unsigned long long mk = __ballot(pred);
        if (pred) {
            int slot = base + (int)__popcll(mk & ((1ull << lane) - 1ull));
            if (slot < MAXC) { s_ci[wv][slot] = p; s_cd[wv][slot] = d2; }
        }
        base += (int)__popcll(mk);
    }
    int cc = min(base, MAXC);
    __syncthreads();
    if (cc <= 32) {
        if (lane < cc) nbr_idx[m * 32 + lane] = s_ci[wv][lane];
        if (lane == 0) nbr_cnt[m] = cc;
    } else {
        int ng = (cc + 63) >> 6;
        for (int g = 0; g < ng; g++) {
            int i = g * 64 + lane;
            if (i < cc) {
                float di = s_cd[wv][i]; int pi = s_ci[wv][i];
                int rank = 0;
                for (int j = 0; j < cc; j++) {
                    float dj = s_cd[wv][j]; int pj = s_ci[wv][j];
                    rank += (dj < di || (dj == di && pj < pi)) ? 1 : 0;
                }
                if (rank < 32) nbr_idx[m * 32 + rank] = pi;
            }
        }
        if (lane == 0) nbr_cnt[m] = 32;
    }
}

// ---------------- fused gather + 3-layer MLP (f16 MFMA) + masked maxpool ----------------
__global__ __launch_bounds__(256) void k_mlp(const float* __restrict__ x,
    const float4* __restrict__ pos4, const float4* __restrict__ centers,
    const int* __restrict__ nbr_cnt, const int* __restrict__ nbr_idx,
    const _Float16* __restrict__ w1t, const _Float16* __restrict__ w2t,
    const _Float16* __restrict__ w3t,
    const float* __restrict__ b1, const float* __restrict__ b2, const float* __restrict__ b3,
    float* __restrict__ out)
{
    __shared__ __align__(16) _Float16 sA[64 * 168];    // X tile: feat(128)+rel(3)+pad, K=160 used
    __shared__ __align__(16) _Float16 sW[256 * 136];   // union: W1T(128x168) / W2T(128x136) / W3T(256x136)
    __shared__ __align__(16) _Float16 sH1[64 * 136];
    __shared__ __align__(16) _Float16 sH2[64 * 136];
    __shared__ float s_pool[4][256];
    __shared__ int s_cnt[2];

    const int t = threadIdx.x, lane = t & 63, wv = t >> 6;
    const int bid = blockIdx.x;

    // ---- stage A (gather rows for 2 centers = 64 rows) ----
    {
        int r = t >> 2, tsub = t & 3;
        int g = r >> 5, s = r & 31;
        int m = bid * 2 + g;
        int cnt = nbr_cnt[m];
        if (t < 2) s_cnt[t] = nbr_cnt[bid * 2 + t];
        _Float16* row = &sA[r * 168];
        if (s < cnt) {
            int col = nbr_idx[m * 32 + s];
            const float* fx = x + (long)col * 131 + 3;
            for (int k = tsub * 32; k < tsub * 32 + 32; k++) row[k] = (_Float16)fx[k];
            if (tsub == 0) {
                float4 ctr = centers[m];
                float4 pp = pos4[col];
                row[128] = (_Float16)(pp.x - ctr.x);
                row[129] = (_Float16)(pp.y - ctr.y);
                row[130] = (_Float16)(pp.z - ctr.z);
                for (int k = 131; k < 168; k++) row[k] = (_Float16)0.f;
            }
        } else {
            for (int k = tsub * 32; k < tsub * 32 + 32; k++) row[k] = (_Float16)0.f;
            if (tsub == 0) for (int k = 128; k < 168; k++) row[k] = (_Float16)0.f;
        }
    }
    // copy W1T
    {
        const uint4* src = (const uint4*)w1t; uint4* dst = (uint4*)sW;
        for (int i = t; i < (128 * 168) / 8; i += 256) dst[i] = src[i];
    }
    __syncthreads();

    const int cl = lane & 15;
    const int kgrp = (lane >> 4) * 8;
    const int rsub = (lane >> 4) * 4;
    const int R0 = wv * 16;

    // ---- GEMM1: [64x160] @ W1T -> relu -> sH1 ----
    {
        f32x4 acc[8];
        #pragma unroll
        for (int i = 0; i < 8; i++) acc[i] = (f32x4){0.f, 0.f, 0.f, 0.f};
        #pragma unroll
        for (int ks = 0; ks < 5; ks++) {
            int kb = ks * 32 + kgrp;
            f16x8 a = *(const f16x8*)&sA[(R0 + cl) * 168 + kb];
            #pragma unroll
            for (int ct = 0; ct < 8; ct++) {
                f16x8 b = *(const f16x8*)&sW[(ct * 16 + cl) * 168 + kb];
                acc[ct] = __builtin_amdgcn_mfma_f32_16x16x32_f16(a, b, acc[ct], 0, 0, 0);
            }
        }
        #pragma unroll
        for (int ct = 0; ct < 8; ct++) {
            int c = ct * 16 + cl;
            float bb = b1[c];
            #pragma unroll
            for (int v = 0; v < 4; v++) {
                float val = fmaxf(acc[ct][v] + bb, 0.f);
                sH1[(R0 + rsub + v) * 136 + c] = (_Float16)val;
            }
        }
    }
    __syncthreads();
    // copy W2T
    {
        const uint4* src = (const uint4*)w2t; uint4* dst = (uint4*)sW;
        for (int i = t; i < (128 * 136) / 8; i += 256) dst[i] = src[i];
    }
    __syncthreads();
    // ---- GEMM2: [64x128] @ W2T -> relu -> sH2 ----
    {
        f32x4 acc[8];
        #pragma unroll
        for (int i = 0; i < 8; i++) acc[i] = (f32x4){0.f, 0.f, 0.f, 0.f};
        #pragma unroll
        for (int ks = 0; ks < 4; ks++) {
            int kb = ks * 32 + kgrp;
            f16x8 a = *(const f16x8*)&sH1[(R0 + cl) * 136 + kb];
            #pragma unroll
            for (int ct = 0; ct < 8; ct++) {
                f16x8 b = *(const f16x8*)&sW[(ct * 16 + cl) * 136 + kb];
                acc[ct] = __builtin_amdgcn_mfma_f32_16x16x32_f16(a, b, acc[ct], 0, 0, 0);
            }
        }
        #pragma unroll
        for (int ct = 0; ct < 8; ct++) {
            int c = ct * 16 + cl;
            float bb = b2[c];
            #pragma unroll
            for (int v = 0; v < 4; v++) {
                float val = fmaxf(acc[ct][v] + bb, 0.f);
                sH2[(R0 + rsub + v) * 136 + c] = (_Float16)val;
            }
        }
    }
    __syncthreads();
    // copy W3T
    {
        const uint4* src = (const uint4*)w3t; uint4* dst = (uint4*)sW;
        for (int i = t; i < (256 * 136) / 8; i += 256) dst[i] = src[i];
    }
    __syncthreads();
    // ---- GEMM3: [64x128] @ W3T (N=256) -> relu -> masked maxpool ----
    {
        f32x4 acc[16];
        #pragma unroll
        for (int i = 0; i < 16; i++) acc[i] = (f32x4){0.f, 0.f, 0.f, 0.f};
        #pragma unroll
        for (int ks = 0; ks < 4; ks++) {
            int kb = ks * 32 + kgrp;
            f16x8 a = *(const f16x8*)&sH2[(R0 + cl) * 136 + kb];
            #pragma unroll
            for (int ct = 0; ct < 16; ct++) {
                f16x8 b = *(const f16x8*)&sW[(ct * 16 + cl) * 136 + kb];
                acc[ct] = __builtin_amdgcn_mfma_f32_16x16x32_f16(a, b, acc[ct], 0, 0, 0);
            }
        }
        int cnt = s_cnt[wv >> 1];
        #pragma unroll
        for (int ct = 0; ct < 16; ct++) {
            int c = ct * 16 + cl;
            float bb = b3[c];
            float p = -__builtin_inff();
            #pragma unroll
            for (int v = 0; v < 4; v++) {
                int srow = (wv & 1) * 16 + rsub + v;   // slot within center [0,32)
                float val = fmaxf(acc[ct][v] + bb, 0.f);
                if (srow < cnt) p = fmaxf(p, val);
            }
            p = fmaxf(p, __shfl_xor(p, 16));
            p = fmaxf(p, __shfl_xor(p, 32));
            if (lane < 16) s_pool[wv][ct * 16 + lane] = p;
        }
    }
    __syncthreads();
    {
        float p0 = fmaxf(s_pool[0][t], s_pool[1][t]);
        float p1 = fmaxf(s_pool[2][t], s_pool[3][t]);
        out[(bid * 2 + 0) * 256 + t] = p0;
        out[(bid * 2 + 1) * 256 + t] = p1;
    }
}

extern "C" void kernel_launch(void* const* d_in, const int* in_sizes, int n_in,
                              void* d_out, int out_size, void* d_ws, size_t ws_size,
                              hipStream_t stream)
{
    const float* x  = (const float*)d_in[0];
    const float* W1 = (const float*)d_in[1];
    const float* b1 = (const float*)d_in[2];
    const float* W2 = (const float*)d_in[3];
    const float* b2 = (const float*)d_in[4];
    const float* W3 = (const float*)d_in[5];
    const float* b3 = (const float*)d_in[6];
    float* out = (float*)d_out;

    char* w = (char*)d_ws;
    float4* pos4    = (float4*)(w + 0);         // 262144 B
    float4* centers = (float4*)(w + 262144);    // 65536 B
    int* nbr_cnt    = (int*)(w + 327680);       // 16384 B
    int* nbr_idx    = (int*)(w + 344064);       // 524288 B
    _Float16* w1t   = (_Float16*)(w + 868352);  // 43008 B
    _Float16* w2t   = (_Float16*)(w + 911360);  // 34816 B
    _Float16* w3t   = (_Float16*)(w + 946176);  // 69632 B -> end 1015808 B

    k_prep<<<352, 256, 0, stream>>>(x, W1, W2, W3, pos4, w1t, w2t, w3t);
    k_fps<<<1, 1024, 0, stream>>>(pos4, centers);
    k_knn<<<1024, 256, 0, stream>>>(pos4, centers, nbr_cnt, nbr_idx);
    k_mlp<<<2048, 256, 0, stream>>>(x, pos4, centers, nbr_cnt, nbr_idx,
                                    w1t, w2t, w3t, b1, b2, b3, out);
}

// Round 3
// 7286.222 us; speedup vs baseline: 2.3549x; 2.3549x over previous
//
#include <hip/hip_runtime.h>
#include <hip/hip_fp16.h>

#define NP 16384
#define MC 4096
#define R2F 0.04f
#define MAXC 256

typedef _Float16 f16x8 __attribute__((ext_vector_type(8)));
typedef float f32x4 __attribute__((ext_vector_type(4)));

// Reference-matching squared distance: (dx*dx + dy*dy) + dz*dz, no fma contraction.
__device__ __forceinline__ float sqdist3(float ax, float ay, float az,
                                         float bx, float by, float bz) {
    float dx = ax - bx, dy = ay - by, dz = az - bz;
    return __fadd_rn(__fadd_rn(__fmul_rn(dx, dx), __fmul_rn(dy, dy)), __fmul_rn(dz, dz));
}

// ---------------- prep: pos4 + transposed f16 weights ----------------
__global__ __launch_bounds__(256) void k_prep(const float* __restrict__ x,
    const float* __restrict__ W1, const float* __restrict__ W2, const float* __restrict__ W3,
    float4* __restrict__ pos4, _Float16* __restrict__ w1t,
    _Float16* __restrict__ w2t, _Float16* __restrict__ w3t)
{
    int tid = blockIdx.x * 256 + threadIdx.x;
    if (tid < NP) {
        long b = (long)tid * 131;
        float4 p; p.x = x[b]; p.y = x[b + 1]; p.z = x[b + 2]; p.w = 0.f;
        pos4[tid] = p;
    } else if (tid < NP + 128 * 168) {
        int i = tid - NP; int c = i / 168, k = i % 168;
        w1t[i] = (k < 131) ? (_Float16)W1[k * 128 + c] : (_Float16)0.f;
    } else if (tid < NP + 128 * 168 + 128 * 136) {
        int i = tid - (NP + 128 * 168); int c = i / 136, k = i % 136;
        w2t[i] = (k < 128) ? (_Float16)W2[k * 128 + c] : (_Float16)0.f;
    } else if (tid < NP + 128 * 168 + 128 * 136 + 256 * 136) {
        int i = tid - (NP + 128 * 168 + 128 * 136); int c = i / 136, k = i % 136;
        w3t[i] = (k < 128) ? (_Float16)W3[k * 256 + c] : (_Float16)0.f;
    }
}

// ---------------- FPS: single workgroup, 512 thr, packed-key single-barrier loop ----------------
__global__ __launch_bounds__(512) void k_fps(const float4* __restrict__ pos4,
                                             float4* __restrict__ centers)
{
    __shared__ unsigned long long s_key[2][8];
    const int t = threadIdx.x;
    const int lane = t & 63;
    const int wv = t >> 6;
    float px[32], py[32], pz[32], md[32];
    #pragma unroll
    for (int i = 0; i < 32; i++) {
        float4 p = pos4[i * 512 + t];           // coalesced; thread owns pts i*512+t
        px[i] = p.x; py[i] = p.y; pz[i] = p.z;
        md[i] = __builtin_inff();
    }
    float4 c0 = pos4[0];
    float cx = c0.x, cy = c0.y, cz = c0.z;
    if (t == 0) centers[0] = make_float4(cx, cy, cz, 0.f);
    for (int m = 0; m < MC - 1; m++) {
        float lv = -1.f; int li = 0;
        #pragma unroll
        for (int i = 0; i < 32; i++) {
            float d = sqdist3(px[i], py[i], pz[i], cx, cy, cz);
            float nmd = fminf(md[i], d);
            md[i] = nmd;
            bool gt = nmd > lv;                 // strict >: first (lowest i) max wins
            lv = gt ? nmd : lv;
            li = gt ? i : li;
        }
        // key: high = float bits of max-min-dist (monotone for d>=0), low = ~global_idx
        // u64 max => max distance, tie -> min global index (matches jnp.argmax first-hit)
        unsigned long long key =
            ((unsigned long long)__float_as_uint(lv) << 32) |
            (unsigned long long)(unsigned)~(unsigned)(li * 512 + t);
        #pragma unroll
        for (int off = 1; off < 64; off <<= 1) {
            unsigned long long o = __shfl_xor(key, off);
            key = (o > key) ? o : key;
        }
        if (lane == 0) s_key[m & 1][wv] = key;  // parity double-buffer kills WAR race
        __syncthreads();                        // the ONLY barrier per iteration
        key = s_key[m & 1][lane & 7];
        #pragma unroll
        for (int off = 1; off < 8; off <<= 1) {
            unsigned long long o = __shfl_xor(key, off);
            key = (o > key) ? o : key;
        }
        int idx = (int)~(unsigned)(key & 0xffffffffull);
        float4 c4 = pos4[idx];                  // wave-uniform broadcast load, L2-hot
        cx = c4.x; cy = c4.y; cz = c4.z;
        if (t == 0) centers[m + 1] = make_float4(cx, cy, cz, 0.f);
    }
}

// ---------------- kNN within radius: one wave per center ----------------
__global__ __launch_bounds__(256) void k_knn(const float4* __restrict__ pos4,
                                             const float4* __restrict__ centers,
                                             int* __restrict__ nbr_cnt,
                                             int* __restrict__ nbr_idx)
{
    __shared__ int s_ci[4][MAXC];
    __shared__ float s_cd[4][MAXC];
    const int t = threadIdx.x, lane = t & 63, wv = t >> 6;
    const int m = blockIdx.x * 4 + wv;
    float4 c = centers[m];
    int base = 0;
    for (int ch = 0; ch < NP / 64; ch++) {
        int p = ch * 64 + lane;
        float4 q = pos4[p];
        float d2 = sqdist3(q.x, q.y, q.z, c.x, c.y, c.z);
        bool pred = (d2 <= R2F);
        unsigned long long mk = __ballot(pred);
        if (pred) {
            int slot = base + (int)__popcll(mk & ((1ull << lane) - 1ull));
            if (slot < MAXC) { s_ci[wv][slot] = p; s_cd[wv][slot] = d2; }
        }
        base += (int)__popcll(mk);
    }
    int cc = min(base, MAXC);
    __syncthreads();
    if (cc <= 32) {
        if (lane < cc) nbr_idx[m * 32 + lane] = s_ci[wv][lane];
        if (lane == 0) nbr_cnt[m] = cc;
    } else {
        int ng = (cc + 63) >> 6;
        for (int g = 0; g < ng; g++) {
            int i = g * 64 + lane;
            if (i < cc) {
                float di = s_cd[wv][i]; int pi = s_ci[wv][i];
                int rank = 0;
                for (int j = 0; j < cc; j++) {
                    float dj = s_cd[wv][j]; int pj = s_ci[wv][j];
                    rank += (dj < di || (dj == di && pj < pi)) ? 1 : 0;
                }
                if (rank < 32) nbr_idx[m * 32 + rank] = pi;
            }
        }
        if (lane == 0) nbr_cnt[m] = 32;
    }
}

// ---------------- fused gather + 3-layer MLP (f16 MFMA) + masked maxpool ----------------
__global__ __launch_bounds__(256) void k_mlp(const float* __restrict__ x,
    const float4* __restrict__ pos4, const float4* __restrict__ centers,
    const int* __restrict__ nbr_cnt, const int* __restrict__ nbr_idx,
    const _Float16* __restrict__ w1t, const _Float16* __restrict__ w2t,
    const _Float16* __restrict__ w3t,
    const float* __restrict__ b1, const float* __restrict__ b2, const float* __restrict__ b3,
    float* __restrict__ out)
{
    __shared__ __align__(16) _Float16 sA[64 * 168];    // X tile: feat(128)+rel(3)+pad, K=160 used
    __shared__ __align__(16) _Float16 sW[256 * 136];   // union: W1T(128x168) / W2T(128x136) / W3T(256x136)
    __shared__ __align__(16) _Float16 sH1[64 * 136];
    __shared__ __align__(16) _Float16 sH2[64 * 136];
    __shared__ float s_pool[4][256];
    __shared__ int s_cnt[2];

    const int t = threadIdx.x, lane = t & 63, wv = t >> 6;
    const int bid = blockIdx.x;

    // ---- stage A (gather rows for 2 centers = 64 rows) ----
    {
        int r = t >> 2, tsub = t & 3;
        int g = r >> 5, s = r & 31;
        int m = bid * 2 + g;
        int cnt = nbr_cnt[m];
        if (t < 2) s_cnt[t] = nbr_cnt[bid * 2 + t];
        _Float16* row = &sA[r * 168];
        if (s < cnt) {
            int col = nbr_idx[m * 32 + s];
            const float* fx = x + (long)col * 131 + 3;
            for (int k = tsub * 32; k < tsub * 32 + 32; k++) row[k] = (_Float16)fx[k];
            if (tsub == 0) {
                float4 ctr = centers[m];
                float4 pp = pos4[col];
                row[128] = (_Float16)(pp.x - ctr.x);
                row[129] = (_Float16)(pp.y - ctr.y);
                row[130] = (_Float16)(pp.z - ctr.z);
                for (int k = 131; k < 168; k++) row[k] = (_Float16)0.f;
            }
        } else {
            for (int k = tsub * 32; k < tsub * 32 + 32; k++) row[k] = (_Float16)0.f;
            if (tsub == 0) for (int k = 128; k < 168; k++) row[k] = (_Float16)0.f;
        }
    }
    // copy W1T
    {
        const uint4* src = (const uint4*)w1t; uint4* dst = (uint4*)sW;
        for (int i = t; i < (128 * 168) / 8; i += 256) dst[i] = src[i];
    }
    __syncthreads();

    const int cl = lane & 15;
    const int kgrp = (lane >> 4) * 8;
    const int rsub = (lane >> 4) * 4;
    const int R0 = wv * 16;

    // ---- GEMM1: [64x160] @ W1T -> relu -> sH1 ----
    {
        f32x4 acc[8];
        #pragma unroll
        for (int i = 0; i < 8; i++) acc[i] = (f32x4){0.f, 0.f, 0.f, 0.f};
        #pragma unroll
        for (int ks = 0; ks < 5; ks++) {
            int kb = ks * 32 + kgrp;
            f16x8 a = *(const f16x8*)&sA[(R0 + cl) * 168 + kb];
            #pragma unroll
            for (int ct = 0; ct < 8; ct++) {
                f16x8 b = *(const f16x8*)&sW[(ct * 16 + cl) * 168 + kb];
                acc[ct] = __builtin_amdgcn_mfma_f32_16x16x32_f16(a, b, acc[ct], 0, 0, 0);
            }
        }
        #pragma unroll
        for (int ct = 0; ct < 8; ct++) {
            int c = ct * 16 + cl;
            float bb = b1[c];
            #pragma unroll
            for (int v = 0; v < 4; v++) {
                float val = fmaxf(acc[ct][v] + bb, 0.f);
                sH1[(R0 + rsub + v) * 136 + c] = (_Float16)val;
            }
        }
    }
    __syncthreads();
    // copy W2T
    {
        const uint4* src = (const uint4*)w2t; uint4* dst = (uint4*)sW;
        for (int i = t; i < (128 * 136) / 8; i += 256) dst[i] = src[i];
    }
    __syncthreads();
    // ---- GEMM2: [64x128] @ W2T -> relu -> sH2 ----
    {
        f32x4 acc[8];
        #pragma unroll
        for (int i = 0; i < 8; i++) acc[i] = (f32x4){0.f, 0.f, 0.f, 0.f};
        #pragma unroll
        for (int ks = 0; ks < 4; ks++) {
            int kb = ks * 32 + kgrp;
            f16x8 a = *(const f16x8*)&sH1[(R0 + cl) * 136 + kb];
            #pragma unroll
            for (int ct = 0; ct < 8; ct++) {
                f16x8 b = *(const f16x8*)&sW[(ct * 16 + cl) * 136 + kb];
                acc[ct] = __builtin_amdgcn_mfma_f32_16x16x32_f16(a, b, acc[ct], 0, 0, 0);
            }
        }
        #pragma unroll
        for (int ct = 0; ct < 8; ct++) {
            int c = ct * 16 + cl;
            float bb = b2[c];
            #pragma unroll
            for (int v = 0; v < 4; v++) {
                float val = fmaxf(acc[ct][v] + bb, 0.f);
                sH2[(R0 + rsub + v) * 136 + c] = (_Float16)val;
            }
        }
    }
    __syncthreads();
    // copy W3T
    {
        const uint4* src = (const uint4*)w3t; uint4* dst = (uint4*)sW;
        for (int i = t; i < (256 * 136) / 8; i += 256) dst[i] = src[i];
    }
    __syncthreads();
    // ---- GEMM3: [64x128] @ W3T (N=256) -> relu -> masked maxpool ----
    {
        f32x4 acc[16];
        #pragma unroll
        for (int i = 0; i < 16; i++) acc[i] = (f32x4){0.f, 0.f, 0.f, 0.f};
        #pragma unroll
        for (int ks = 0; ks < 4; ks++) {
            int kb = ks * 32 + kgrp;
            f16x8 a = *(const f16x8*)&sH2[(R0 + cl) * 136 + kb];
            #pragma unroll
            for (int ct = 0; ct < 16; ct++) {
                f16x8 b = *(const f16x8*)&sW[(ct * 16 + cl) * 136 + kb];
                acc[ct] = __builtin_amdgcn_mfma_f32_16x16x32_f16(a, b, acc[ct], 0, 0, 0);
            }
        }
        int cnt = s_cnt[wv >> 1];
        #pragma unroll
        for (int ct = 0; ct < 16; ct++) {
            int c = ct * 16 + cl;
            float bb = b3[c];
            float p = -__builtin_inff();
            #pragma unroll
            for (int v = 0; v < 4; v++) {
                int srow = (wv & 1) * 16 + rsub + v;   // slot within center [0,32)
                float val = fmaxf(acc[ct][v] + bb, 0.f);
                if (srow < cnt) p = fmaxf(p, val);
            }
            p = fmaxf(p, __shfl_xor(p, 16));
            p = fmaxf(p, __shfl_xor(p, 32));
            if (lane < 16) s_pool[wv][ct * 16 + lane] = p;
        }
    }
    __syncthreads();
    {
        float p0 = fmaxf(s_pool[0][t], s_pool[1][t]);
        float p1 = fmaxf(s_pool[2][t], s_pool[3][t]);
        out[(bid * 2 + 0) * 256 + t] = p0;
        out[(bid * 2 + 1) * 256 + t] = p1;
    }
}

extern "C" void kernel_launch(void* const* d_in, const int* in_sizes, int n_in,
                              void* d_out, int out_size, void* d_ws, size_t ws_size,
                              hipStream_t stream)
{
    const float* x  = (const float*)d_in[0];
    const float* W1 = (const float*)d_in[1];
    const float* b1 = (const float*)d_in[2];
    const float* W2 = (const float*)d_in[3];
    const float* b2 = (const float*)d_in[4];
    const float* W3 = (const float*)d_in[5];
    const float* b3 = (const float*)d_in[6];
    float* out = (float*)d_out;

    char* w = (char*)d_ws;
    float4* pos4    = (float4*)(w + 0);         // 262144 B
    float4* centers = (float4*)(w + 262144);    // 65536 B
    int* nbr_cnt    = (int*)(w + 327680);       // 16384 B
    int* nbr_idx    = (int*)(w + 344064);       // 524288 B
    _Float16* w1t   = (_Float16*)(w + 868352);  // 43008 B
    _Float16* w2t   = (_Float16*)(w + 911360);  // 34816 B
    _Float16* w3t   = (_Float16*)(w + 946176);  // 69632 B -> end 1015808 B

    k_prep<<<352, 256, 0, stream>>>(x, W1, W2, W3, pos4, w1t, w2t, w3t);
    k_fps<<<1, 512, 0, stream>>>(pos4, centers);
    k_knn<<<1024, 256, 0, stream>>>(pos4, centers, nbr_cnt, nbr_idx);
    k_mlp<<<2048, 256, 0, stream>>>(x, pos4, centers, nbr_cnt, nbr_idx,
                                    w1t, w2t, w3t, b1, b2, b3, out);
}